// Round 8
// baseline (2289.690 us; speedup 1.0000x reference)
//
#include <hip/hip_runtime.h>

#define HH 128
#define WW 128
#define HWSZ (HH * WW)
#define CC 64
#define OO 64
#define BB 4
#define NOFF 18
#define KK 576          // C*9
#define NBLK (BB * HWSZ / 64)   // 1024 fused blocks

// ws layout (dword offsets)
#define WS_BG     0                         // 72*64*4 = 18432 (deform weights, quad-packed)
#define WS_BGO    18432                     // 72*32*4 = 9216  (offset weights, quad-packed, N=32)
#define WS_SUMS2  27648                     // 128 folded stats (sums ++ sumsq)
#define WS_CTL    27776                     // [0] arrival counter, [1] release flag
#define WS_PART   2125952                   // 128 slots x 1024 blocks (slot-major) = 512 KB

typedef __attribute__((ext_vector_type(8))) short short8;
typedef __attribute__((ext_vector_type(4))) int int4v;
typedef __attribute__((ext_vector_type(4))) float f32x4;

__device__ inline unsigned bf16rne(float f) {
  unsigned u = __float_as_uint(f);
  u += 0x7fff + ((u >> 16) & 1);
  return u >> 16;
}

// One kernel: NHWC-bf16 transpose (blocks 0..511) + weight repack + barrier
// control-word zero (blocks 512..575).
__global__ __launch_bounds__(256) void prep_kernel(
    const float* __restrict__ x, const float* __restrict__ off_w,
    const float* __restrict__ dc_w, unsigned int* __restrict__ xTu,
    int* __restrict__ Bg, int* __restrict__ Bgo, unsigned int* __restrict__ ctl) {
  int bid = blockIdx.x;
  if (bid < BB * HH) {
    __shared__ float T[CC][WW + 1];
    int b = bid >> 7, h = bid & 127;
    const float* xp = x + (size_t)b * CC * HWSZ + h * WW;
    int j = threadIdx.x;
#pragma unroll
    for (int i = 0; i < 8; ++i) {
      int l = i * 256 + j;
      int c = l >> 5, w4 = l & 31;
      float4 v = *(const float4*)(xp + (size_t)c * HWSZ + w4 * 4);
      T[c][w4 * 4 + 0] = v.x;
      T[c][w4 * 4 + 1] = v.y;
      T[c][w4 * 4 + 2] = v.z;
      T[c][w4 * 4 + 3] = v.w;
    }
    __syncthreads();
    int c2 = threadIdx.x & 31, wq = threadIdx.x >> 5;
    unsigned int* op = xTu + ((size_t)(b * HH + h) * WW) * 32;
#pragma unroll 8
    for (int i = 0; i < 16; ++i) {
      int w = i * 8 + wq;
      unsigned pk = bf16rne(T[2 * c2][w]) | (bf16rne(T[2 * c2 + 1][w]) << 16);
      op[w * 32 + c2] = pk;
    }
  } else {
    int pb = bid - BB * HH;
    int tid = pb * 256 + threadIdx.x;
    int stride = 64 * 256;
    for (int i = tid; i < 72 * 64 * 4; i += stride) {
      int j = i & 3, o = (i >> 2) & 63, g = i >> 8;
      int k2 = g * 4 + j, t = k2 >> 5, jj = k2 & 31;
      unsigned lo = bf16rne(dc_w[o * KK + (2 * jj) * 9 + t]);
      unsigned hi = bf16rne(dc_w[o * KK + (2 * jj + 1) * 9 + t]);
      Bg[i] = (int)(lo | (hi << 16));
    }
    for (int i = tid; i < 72 * 32 * 4; i += stride) {
      int j = i & 3, o = (i >> 2) & 31, g = i >> 7;
      int k2 = g * 4 + j, t = k2 >> 5, jj = k2 & 31;
      unsigned pk = 0;
      if (o < NOFF) {
        unsigned lo = bf16rne(off_w[o * KK + (2 * jj) * 9 + t]);
        unsigned hi = bf16rne(off_w[o * KK + (2 * jj + 1) * 9 + t]);
        pk = lo | (hi << 16);
      }
      Bgo[i] = (int)pk;
    }
    if (tid < 2) ctl[tid] = 0u;   // arrival counter + release flag
  }
}

// ---- phase-3 gather macros --------------------------------------------------
#define G_ISSUE(i, T, PH)                                                     \
  int4v m##i, da##i, db##i, dcv##i, dd##i;                                    \
  {                                                                           \
    m##i = *(const int4v*)&Mw[(((PH) * 8 + p8) * 9 + (T)) * 4];               \
    unsigned x_ = (unsigned)m##i.x, y_ = (unsigned)m##i.y;                    \
    da##i  = *(const int4v*)&xbu[(x_ & 0xffffu) * 32 + cq4];                  \
    db##i  = *(const int4v*)&xbu[(x_ >> 16) * 32 + cq4];                      \
    dcv##i = *(const int4v*)&xbu[(y_ & 0xffffu) * 32 + cq4];                  \
    dd##i  = *(const int4v*)&xbu[(y_ >> 16) * 32 + cq4];                      \
  }

#define G_BLEND(i, T, PH)                                                     \
  {                                                                           \
    float w00_ = __uint_as_float(((unsigned)m##i.z) << 16);                   \
    float w01_ = __uint_as_float(((unsigned)m##i.z) & 0xffff0000u);           \
    float w10_ = __uint_as_float(((unsigned)m##i.w) << 16);                   \
    float w11_ = __uint_as_float(((unsigned)m##i.w) & 0xffff0000u);           \
    int4v pk_;                                                                \
    _Pragma("unroll")                                                         \
    for (int j = 0; j < 4; ++j) {                                             \
      float slo_ = w00_ * __uint_as_float(((unsigned)da##i[j]) << 16);        \
      slo_ = fmaf(w01_, __uint_as_float(((unsigned)db##i[j]) << 16), slo_);   \
      slo_ = fmaf(w10_, __uint_as_float(((unsigned)dcv##i[j]) << 16), slo_);  \
      slo_ = fmaf(w11_, __uint_as_float(((unsigned)dd##i[j]) << 16), slo_);   \
      float shi_ = w00_ * __uint_as_float(((unsigned)da##i[j]) & 0xffff0000u);\
      shi_ = fmaf(w01_, __uint_as_float(((unsigned)db##i[j]) & 0xffff0000u), shi_);\
      shi_ = fmaf(w10_, __uint_as_float(((unsigned)dcv##i[j]) & 0xffff0000u), shi_);\
      shi_ = fmaf(w11_, __uint_as_float(((unsigned)dd##i[j]) & 0xffff0000u), shi_);\
      pk_[j] = (int)__builtin_amdgcn_perm(__float_as_uint(shi_) + 0x8000u,    \
                                          __float_as_uint(slo_) + 0x8000u,    \
                                          0x07060302u);                       \
    }                                                                         \
    *(int4v*)&A[abase + ((T) & 1) * 544 + ((PH) * 8 + p8) * 34 + cq4] = pk_;  \
  }

#define MFMA_TAP(T)                                                           \
  {                                                                           \
    _Pragma("unroll")                                                         \
    for (int kk2 = 0; kk2 < 2; ++kk2) {                                       \
      int4v av = *(const int4v*)&A[abase + ((T) & 1) * 544 + n16 * 34 + kk2 * 16 + q * 4]; \
      short8 af = __builtin_bit_cast(short8, av);                             \
      int g = (T) * 8 + kk2 * 4 + q;                                          \
      _Pragma("unroll")                                                       \
      for (int nt = 0; nt < 4; ++nt) {                                        \
        int4v bv = *(const int4v*)&Bg[(g * 64 + nt * 16 + n16) * 4];          \
        short8 bfr = __builtin_bit_cast(short8, bv);                          \
        acc[nt] = __builtin_amdgcn_mfma_f32_16x16x32_bf16(af, bfr, acc[nt], 0, 0, 0); \
      }                                                                       \
    }                                                                         \
  }

// Fused offset-conv + deform-conv + BN-stats + grid-barrier + BN-apply.
// y never leaves the accumulator registers. Grid barrier = counter/flag with
// agent-scope atomics (G16: per-XCD L2s non-coherent -> sc1 write-through).
// Residency: LDS 26,624 B -> 6 blocks/CU; VGPR capped 85 by launch_bounds;
// capacity 1536 >= grid 1024 -> all blocks co-resident, spin is safe.
__global__ __launch_bounds__(256, 6) void fused_kernel(
    const unsigned int* __restrict__ xTu, const int* __restrict__ Bg,
    const int* __restrict__ Bgo, const float* __restrict__ off_b,
    const float* __restrict__ dc_b, const float* __restrict__ gamma,
    const float* __restrict__ beta, float* __restrict__ part,
    float* __restrict__ sums2, unsigned int* __restrict__ ctl,
    float* __restrict__ out) {
  __shared__ __align__(16) int A[4 * 1088];    // 17.4 KB
  __shared__ __align__(16) int M[4 * 144 * 4]; // 9.2 KB meta (later: red/flag)

  int cg = threadIdx.x >> 6, lane = threadIdx.x & 63;
  int b = blockIdx.x >> 8, rem = blockIdx.x & 255;
  int h = rem >> 1, w0 = (rem & 1) * 64;
  int hw0 = h * WW + w0;
  int p0 = cg * 16;
  int abase = cg * 1088;
  int n16 = lane & 15, q = lane >> 4;
  int pg = lane >> 3, part8 = lane & 7;
  const unsigned int* xbu = xTu + (size_t)b * HWSZ * 32;

  // ---------- phase 1: offset conv (per-tap im2col + MFMA) ----------
  f32x4 acc2[2] = {f32x4{0, 0, 0, 0}, f32x4{0, 0, 0, 0}};
#pragma unroll
  for (int t = 0; t < 9; ++t) {
    int ky = t / 3 - 1, kx = t % 3 - 1;
    int cy = h + ky;
    bool vy = (cy >= 0) && (cy < HH);
    int cys = min(max(cy, 0), HH - 1);
    int tb = abase + (t & 1) * 544;
#pragma unroll
    for (int i = 0; i < 2; ++i) {
      int px = i * 8 + pg;
      int cx = w0 + p0 + px + kx;
      bool v = vy && (cx >= 0) && (cx < WW);
      int cxs = min(max(cx, 0), WW - 1);
      int4v val = *(const int4v*)&xbu[(cys * WW + cxs) * 32 + part8 * 4];
      if (!v) { val.x = 0; val.y = 0; val.z = 0; val.w = 0; }
      *(int4v*)&A[tb + px * 34 + part8 * 4] = val;
    }
#pragma unroll
    for (int kk2 = 0; kk2 < 2; ++kk2) {
      int4v av = *(const int4v*)&A[tb + n16 * 34 + kk2 * 16 + q * 4];
      short8 af = __builtin_bit_cast(short8, av);
      int g = t * 8 + kk2 * 4 + q;
#pragma unroll
      for (int nt = 0; nt < 2; ++nt) {
        int4v bv = *(const int4v*)&Bgo[(g * 32 + nt * 16 + n16) * 4];
        short8 bfr = __builtin_bit_cast(short8, bv);
        acc2[nt] = __builtin_amdgcn_mfma_f32_16x16x32_bf16(af, bfr, acc2[nt], 0, 0, 0);
      }
    }
  }
  float* offLw = (float*)&A[abase];
#pragma unroll
  for (int nt = 0; nt < 2; ++nt) {
    int o = nt * 16 + n16;
    if (o < NOFF) {
      float bv = off_b[o];
#pragma unroll
      for (int r = 0; r < 4; ++r) offLw[o * 16 + q * 4 + r] = acc2[nt][r] + bv;
    }
  }

  // ---------- phase 2: bilinear meta (wave-private) ----------
  int* Mw = M + cg * 144 * 4;
#pragma unroll
  for (int it = 0; it < 3; ++it) {
    int m = it * 64 + lane;
    if (m < 144) {
      int pxl = (unsigned)m / 9u;
      int t = m - pxl * 9;
      float dy = offLw[(2 * t) * 16 + pxl];
      float dx = offLw[(2 * t + 1) * 16 + pxl];
      float py = (float)(h + t / 3 - 1) + dy;
      float pxf = (float)(w0 + p0 + pxl + (t % 3) - 1) + dx;
      float fy0 = floorf(py), fx0 = floorf(pxf);
      float ay = py - fy0, ax = pxf - fx0;
      int iy0 = (int)fy0, ix0 = (int)fx0;
      int iy1 = iy0 + 1, ix1 = ix0 + 1;
      float wy0 = 1.0f - ay, wy1 = ay, wx0 = 1.0f - ax, wx1 = ax;
      if (!(iy0 >= 0 && iy0 < HH)) wy0 = 0.0f;
      if (!(iy1 >= 0 && iy1 < HH)) wy1 = 0.0f;
      if (!(ix0 >= 0 && ix0 < WW)) wx0 = 0.0f;
      if (!(ix1 >= 0 && ix1 < WW)) wx1 = 0.0f;
      int cy0 = min(max(iy0, 0), HH - 1), cy1 = min(max(iy1, 0), HH - 1);
      int cx0 = min(max(ix0, 0), WW - 1), cx1 = min(max(ix1, 0), WW - 1);
      int4v mv;
      mv.x = (cy0 * WW + cx0) | ((cy0 * WW + cx1) << 16);
      mv.y = (cy1 * WW + cx0) | ((cy1 * WW + cx1) << 16);
      mv.z = (int)(bf16rne(wy0 * wx0) | (bf16rne(wy0 * wx1) << 16));
      mv.w = (int)(bf16rne(wy1 * wx0) | (bf16rne(wy1 * wx1) << 16));
      *(int4v*)&Mw[m * 4] = mv;
    }
  }

  // ---------- phase 3: per-tap gather (1-tap prefetch) + MFMA ----------
  int p8 = lane >> 3;
  int cq4 = (lane & 7) * 4;
  f32x4 acc[4] = {f32x4{0,0,0,0}, f32x4{0,0,0,0}, f32x4{0,0,0,0}, f32x4{0,0,0,0}};
  G_ISSUE(0, 0, 0)   G_ISSUE(1, 0, 1)
  G_ISSUE(2, 1, 0)   G_ISSUE(3, 1, 1)   G_BLEND(0, 0, 0)   G_BLEND(1, 0, 1)   MFMA_TAP(0)
  G_ISSUE(4, 2, 0)   G_ISSUE(5, 2, 1)   G_BLEND(2, 1, 0)   G_BLEND(3, 1, 1)   MFMA_TAP(1)
  G_ISSUE(6, 3, 0)   G_ISSUE(7, 3, 1)   G_BLEND(4, 2, 0)   G_BLEND(5, 2, 1)   MFMA_TAP(2)
  G_ISSUE(8, 4, 0)   G_ISSUE(9, 4, 1)   G_BLEND(6, 3, 0)   G_BLEND(7, 3, 1)   MFMA_TAP(3)
  G_ISSUE(10, 5, 0)  G_ISSUE(11, 5, 1)  G_BLEND(8, 4, 0)   G_BLEND(9, 4, 1)   MFMA_TAP(4)
  G_ISSUE(12, 6, 0)  G_ISSUE(13, 6, 1)  G_BLEND(10, 5, 0)  G_BLEND(11, 5, 1)  MFMA_TAP(5)
  G_ISSUE(14, 7, 0)  G_ISSUE(15, 7, 1)  G_BLEND(12, 6, 0)  G_BLEND(13, 6, 1)  MFMA_TAP(6)
  G_ISSUE(16, 8, 0)  G_ISSUE(17, 8, 1)  G_BLEND(14, 7, 0)  G_BLEND(15, 7, 1)  MFMA_TAP(7)
  G_BLEND(16, 8, 0)  G_BLEND(17, 8, 1)  MFMA_TAP(8)

  // ---------- epilogue A: bias + per-block stats (y stays in registers) ----
  float* SW = (float*)&A[abase];
#pragma unroll
  for (int nt = 0; nt < 4; ++nt) {
    int o = nt * 16 + n16;
    float bv = dc_b[o];
    float s = 0.0f, ss = 0.0f;
#pragma unroll
    for (int r0 = 0; r0 < 4; ++r0) {
      float v = acc[nt][r0] + bv;
      acc[nt][r0] = v;
      s += v;
      ss += v * v;
    }
    s += __shfl_xor(s, 16);  s += __shfl_xor(s, 32);
    ss += __shfl_xor(ss, 16); ss += __shfl_xor(ss, 32);
    if (lane < 16) {
      SW[nt * 16 + lane] = s;
      SW[64 + nt * 16 + lane] = ss;
    }
  }
  __syncthreads();
  // Slot-major partials, written agent-scope (sc1) so the folding block on a
  // different XCD sees them (per-XCD L2 non-coherent).
  if (threadIdx.x < 64) {
    float ts = 0.0f, tq = 0.0f;
#pragma unroll
    for (int wv = 0; wv < 4; ++wv) {
      const float* Sv = (const float*)&A[wv * 1088];
      ts += Sv[threadIdx.x];
      tq += Sv[64 + threadIdx.x];
    }
    __hip_atomic_store(&part[(size_t)threadIdx.x * 1024 + blockIdx.x], ts,
                       __ATOMIC_RELAXED, __HIP_MEMORY_SCOPE_AGENT);
    __hip_atomic_store(&part[(size_t)(64 + threadIdx.x) * 1024 + blockIdx.x], tq,
                       __ATOMIC_RELAXED, __HIP_MEMORY_SCOPE_AGENT);
  }
  __syncthreads();   // barrier drains each wave's stores (vmcnt 0) before arrive

  // ---------- grid barrier: arrive; last block folds; spin on flag ----------
  int* isLastL = &M[128];
  if (threadIdx.x == 0) {
    unsigned old = __hip_atomic_fetch_add(&ctl[0], 1u, __ATOMIC_ACQ_REL,
                                          __HIP_MEMORY_SCOPE_AGENT);
    *isLastL = (old == (unsigned)(NBLK - 1));
  }
  __syncthreads();
  if (*isLastL) {
    int s = threadIdx.x >> 1, hf = threadIdx.x & 1;
    const float* pp = part + (size_t)s * 1024 + hf * 512;
    float a0 = 0.f, a1 = 0.f, a2 = 0.f, a3 = 0.f;
    for (int i = 0; i < 512; i += 4) {
      a0 += __hip_atomic_load(&pp[i + 0], __ATOMIC_RELAXED, __HIP_MEMORY_SCOPE_AGENT);
      a1 += __hip_atomic_load(&pp[i + 1], __ATOMIC_RELAXED, __HIP_MEMORY_SCOPE_AGENT);
      a2 += __hip_atomic_load(&pp[i + 2], __ATOMIC_RELAXED, __HIP_MEMORY_SCOPE_AGENT);
      a3 += __hip_atomic_load(&pp[i + 3], __ATOMIC_RELAXED, __HIP_MEMORY_SCOPE_AGENT);
    }
    float tot = (a0 + a1) + (a2 + a3);
    tot += __shfl_xor(tot, 1);
    if (hf == 0)
      __hip_atomic_store(&sums2[s], tot, __ATOMIC_RELAXED, __HIP_MEMORY_SCOPE_AGENT);
    __syncthreads();   // drain sums2 stores (all waves)
    if (threadIdx.x == 0)
      __hip_atomic_store(&ctl[1], 1u, __ATOMIC_RELEASE, __HIP_MEMORY_SCOPE_AGENT);
  } else {
    if (threadIdx.x == 0) {
      while (__hip_atomic_load(&ctl[1], __ATOMIC_ACQUIRE,
                               __HIP_MEMORY_SCOPE_AGENT) == 0u)
        __builtin_amdgcn_s_sleep(8);
    }
    __syncthreads();
  }

  // ---------- epilogue B: BN-apply from registers, write out ----------
  float* red = (float*)&M[0];
  if (threadIdx.x < 128)
    red[threadIdx.x] = __hip_atomic_load(&sums2[threadIdx.x], __ATOMIC_RELAXED,
                                         __HIP_MEMORY_SCOPE_AGENT);
  __syncthreads();
  const float invN = 1.0f / (float)(BB * HWSZ);
#pragma unroll
  for (int nt = 0; nt < 4; ++nt) {
    int o = nt * 16 + n16;
    float mean = red[o] * invN;
    float var = red[64 + o] * invN - mean * mean;
    float rstd = rsqrtf(var + 1e-5f);
    float g = gamma[o] * rstd;
    float bta = beta[o] - mean * g;
    f32x4 r;
#pragma unroll
    for (int r0 = 0; r0 < 4; ++r0)
      r[r0] = fmaxf(acc[nt][r0] * g + bta, 0.0f);
    *(f32x4*)(out + (size_t)(b * OO + o) * HWSZ + hw0 + p0 + q * 4) = r;
  }
}

extern "C" void kernel_launch(void* const* d_in, const int* in_sizes, int n_in,
                              void* d_out, int out_size, void* d_ws, size_t ws_size,
                              hipStream_t stream) {
  const float* x     = (const float*)d_in[0];
  const float* off_w = (const float*)d_in[1];
  const float* off_b = (const float*)d_in[2];
  const float* dc_w  = (const float*)d_in[3];
  const float* dc_b  = (const float*)d_in[4];
  const float* gamma = (const float*)d_in[5];
  const float* beta  = (const float*)d_in[6];
  float* ws = (float*)d_ws;
  int*   Bg     = (int*)(ws + WS_BG);
  int*   Bgo    = (int*)(ws + WS_BGO);
  float* sums2  = ws + WS_SUMS2;
  unsigned int* ctl = (unsigned int*)(ws + WS_CTL);
  float* part   = ws + WS_PART;
  float* out = (float*)d_out;
  // d_out (16 MB fp32) doubles as NHWC-bf16 xTu scratch (8 MB); all xTu reads
  // complete before the grid barrier; out writes happen strictly after it.
  unsigned int* xTu = (unsigned int*)d_out;

  prep_kernel<<<BB * HH + 64, 256, 0, stream>>>(x, off_w, dc_w, xTu, Bg, Bgo, ctl);
  fused_kernel<<<NBLK, 256, 0, stream>>>(xTu, Bg, Bgo, off_b, dc_b, gamma, beta,
                                         part, sums2, ctl, out);
}

// Round 9
// 121.369 us; speedup vs baseline: 18.8656x; 18.8656x over previous
//
#include <hip/hip_runtime.h>

#define HH 128
#define WW 128
#define HWSZ (HH * WW)
#define CC 64
#define OO 64
#define BB 4
#define NOFF 18
#define KK 576          // C*9

// ws layout (dword offsets)
#define WS_BG     0                         // 72*64*4 = 18432 (deform weights, quad-packed)
#define WS_BGO    18432                     // 72*32*4 = 9216  (offset weights, quad-packed, N=32)
#define WS_YBUF   27776                     // bf16 y: 4*64*16384*2B = 8 MB (2097152 dwords)
#define WS_PART   2125952                   // 128 slots x 1024 blocks (slot-major) = 512 KB

typedef __attribute__((ext_vector_type(8))) short short8;
typedef __attribute__((ext_vector_type(4))) int int4v;
typedef __attribute__((ext_vector_type(2))) unsigned int uint2v;
typedef __attribute__((ext_vector_type(4))) float f32x4;

__device__ inline unsigned bf16rne(float f) {
  unsigned u = __float_as_uint(f);
  u += 0x7fff + ((u >> 16) & 1);
  return u >> 16;
}

__device__ inline float bf16lo(unsigned u) { return __uint_as_float(u << 16); }
__device__ inline float bf16hi(unsigned u) { return __uint_as_float(u & 0xffff0000u); }

// NHWC-bf16 transpose (blocks 0..1023, 64c x 64w tiles) + weight repack
// (blocks 1024..1087). Tile halved vs R7: 2x blocks (4/CU) to hide the
// strided-read latency chain that made prep latency-bound at 2 blocks/CU.
__global__ __launch_bounds__(256) void prep_kernel(
    const float* __restrict__ x, const float* __restrict__ off_w,
    const float* __restrict__ dc_w, unsigned int* __restrict__ xTu,
    int* __restrict__ Bg, int* __restrict__ Bgo) {
  int bid = blockIdx.x;
  if (bid < BB * HH * 2) {
    __shared__ float T[CC][64 + 1];
    int b = bid >> 8, rem = bid & 255;
    int h = rem >> 1, wh = (rem & 1) * 64;
    const float* xp = x + (size_t)b * CC * HWSZ + h * WW + wh;
    int j = threadIdx.x;
    // 64c x 64w tile = 1024 float4 slots; 4 per thread, fully coalesced.
#pragma unroll
    for (int i = 0; i < 4; ++i) {
      int l = i * 256 + j;
      int c = l >> 4, w4 = l & 15;
      float4 v = *(const float4*)(xp + (size_t)c * HWSZ + w4 * 4);
      T[c][w4 * 4 + 0] = v.x;
      T[c][w4 * 4 + 1] = v.y;
      T[c][w4 * 4 + 2] = v.z;
      T[c][w4 * 4 + 3] = v.w;
    }
    __syncthreads();
    int c2 = threadIdx.x & 31, wq = threadIdx.x >> 5;
    unsigned int* op = xTu + ((size_t)(b * HH + h) * WW + wh) * 32;
#pragma unroll 8
    for (int i = 0; i < 8; ++i) {
      int w = i * 8 + wq;
      unsigned pk = bf16rne(T[2 * c2][w]) | (bf16rne(T[2 * c2 + 1][w]) << 16);
      op[w * 32 + c2] = pk;
    }
  } else {
    int pb = bid - BB * HH * 2;
    int tid = pb * 256 + threadIdx.x;
    int stride = 64 * 256;
    for (int i = tid; i < 72 * 64 * 4; i += stride) {
      int j = i & 3, o = (i >> 2) & 63, g = i >> 8;
      int k2 = g * 4 + j, t = k2 >> 5, jj = k2 & 31;
      unsigned lo = bf16rne(dc_w[o * KK + (2 * jj) * 9 + t]);
      unsigned hi = bf16rne(dc_w[o * KK + (2 * jj + 1) * 9 + t]);
      Bg[i] = (int)(lo | (hi << 16));
    }
    for (int i = tid; i < 72 * 32 * 4; i += stride) {
      int j = i & 3, o = (i >> 2) & 31, g = i >> 7;
      int k2 = g * 4 + j, t = k2 >> 5, jj = k2 & 31;
      unsigned pk = 0;
      if (o < NOFF) {
        unsigned lo = bf16rne(off_w[o * KK + (2 * jj) * 9 + t]);
        unsigned hi = bf16rne(off_w[o * KK + (2 * jj + 1) * 9 + t]);
        pk = lo | (hi << 16);
      }
      Bgo[i] = (int)pk;
    }
  }
}

// ---- phase-3 gather macros --------------------------------------------------
// Lane map: p8 = lane>>3 (pixel slot), cq4 = (lane&7)*4 (channel-quad dword).
// Per-tap double-buffered A: wave region A[cg*1088], buf (t&1)*544,
// row stride 34 dwords (34 = 2 mod 32 -> ~2-4 way banks).
#define G_ISSUE(i, T, PH)                                                     \
  int4v m##i, da##i, db##i, dcv##i, dd##i;                                    \
  {                                                                           \
    m##i = *(const int4v*)&Mw[(((PH) * 8 + p8) * 9 + (T)) * 4];               \
    unsigned x_ = (unsigned)m##i.x, y_ = (unsigned)m##i.y;                    \
    da##i  = *(const int4v*)&xbu[(x_ & 0xffffu) * 32 + cq4];                  \
    db##i  = *(const int4v*)&xbu[(x_ >> 16) * 32 + cq4];                      \
    dcv##i = *(const int4v*)&xbu[(y_ & 0xffffu) * 32 + cq4];                  \
    dd##i  = *(const int4v*)&xbu[(y_ >> 16) * 32 + cq4];                      \
  }

#define G_BLEND(i, T, PH)                                                     \
  {                                                                           \
    float w00_ = __uint_as_float(((unsigned)m##i.z) << 16);                   \
    float w01_ = __uint_as_float(((unsigned)m##i.z) & 0xffff0000u);           \
    float w10_ = __uint_as_float(((unsigned)m##i.w) << 16);                   \
    float w11_ = __uint_as_float(((unsigned)m##i.w) & 0xffff0000u);           \
    int4v pk_;                                                                \
    _Pragma("unroll")                                                         \
    for (int j = 0; j < 4; ++j) {                                             \
      float slo_ = w00_ * __uint_as_float(((unsigned)da##i[j]) << 16);        \
      slo_ = fmaf(w01_, __uint_as_float(((unsigned)db##i[j]) << 16), slo_);   \
      slo_ = fmaf(w10_, __uint_as_float(((unsigned)dcv##i[j]) << 16), slo_);  \
      slo_ = fmaf(w11_, __uint_as_float(((unsigned)dd##i[j]) << 16), slo_);   \
      float shi_ = w00_ * __uint_as_float(((unsigned)da##i[j]) & 0xffff0000u);\
      shi_ = fmaf(w01_, __uint_as_float(((unsigned)db##i[j]) & 0xffff0000u), shi_);\
      shi_ = fmaf(w10_, __uint_as_float(((unsigned)dcv##i[j]) & 0xffff0000u), shi_);\
      shi_ = fmaf(w11_, __uint_as_float(((unsigned)dd##i[j]) & 0xffff0000u), shi_);\
      pk_[j] = (int)__builtin_amdgcn_perm(__float_as_uint(shi_) + 0x8000u,    \
                                          __float_as_uint(slo_) + 0x8000u,    \
                                          0x07060302u);                       \
    }                                                                         \
    *(int4v*)&A[abase + ((T) & 1) * 544 + ((PH) * 8 + p8) * 34 + cq4] = pk_;  \
  }

#define MFMA_TAP(T)                                                           \
  {                                                                           \
    _Pragma("unroll")                                                         \
    for (int kk2 = 0; kk2 < 2; ++kk2) {                                       \
      int4v av = *(const int4v*)&A[abase + ((T) & 1) * 544 + n16 * 34 + kk2 * 16 + q * 4]; \
      short8 af = __builtin_bit_cast(short8, av);                             \
      int g = (T) * 8 + kk2 * 4 + q;                                          \
      _Pragma("unroll")                                                       \
      for (int nt = 0; nt < 4; ++nt) {                                        \
        int4v bv = *(const int4v*)&Bg[(g * 64 + nt * 16 + n16) * 4];          \
        short8 bfr = __builtin_bit_cast(short8, bv);                          \
        acc[nt] = __builtin_amdgcn_mfma_f32_16x16x32_bf16(af, bfr, acc[nt], 0, 0, 0); \
      }                                                                       \
    }                                                                         \
  }

// Fused offset-conv + deform-conv + BN-partials (R7 form, unchanged).
// LDS: per-tap dbuf A (17.4 KB) + M (9.2 KB) = 26,624 B -> 6 blocks/CU.
__global__ __launch_bounds__(256, 6) void fused_kernel(
    const unsigned int* __restrict__ xTu, const int* __restrict__ Bg,
    const int* __restrict__ Bgo, const float* __restrict__ off_b,
    const float* __restrict__ dc_b, unsigned int* __restrict__ ybuf,
    float* __restrict__ part) {
  __shared__ __align__(16) int A[4 * 1088];   // 17.4 KB: 4 waves x 2 bufs x 16px x 34dw
  __shared__ __align__(16) int M[4 * 144 * 4]; // 9.2 KB meta

  int cg = threadIdx.x >> 6, lane = threadIdx.x & 63;
  int b = blockIdx.x >> 8, rem = blockIdx.x & 255;
  int h = rem >> 1, w0 = (rem & 1) * 64;
  int hw0 = h * WW + w0;
  int p0 = cg * 16;
  int abase = cg * 1088;
  int n16 = lane & 15, q = lane >> 4;
  int pg = lane >> 3, part8 = lane & 7;
  const unsigned int* xbu = xTu + (size_t)b * HWSZ * 32;

  // ---------- phase 1: offset conv (per-tap im2col + MFMA) ----------
  f32x4 acc2[2] = {f32x4{0, 0, 0, 0}, f32x4{0, 0, 0, 0}};
#pragma unroll
  for (int t = 0; t < 9; ++t) {
    int ky = t / 3 - 1, kx = t % 3 - 1;
    int cy = h + ky;
    bool vy = (cy >= 0) && (cy < HH);
    int cys = min(max(cy, 0), HH - 1);
    int tb = abase + (t & 1) * 544;
#pragma unroll
    for (int i = 0; i < 2; ++i) {
      int px = i * 8 + pg;
      int cx = w0 + p0 + px + kx;
      bool v = vy && (cx >= 0) && (cx < WW);
      int cxs = min(max(cx, 0), WW - 1);
      int4v val = *(const int4v*)&xbu[(cys * WW + cxs) * 32 + part8 * 4];
      if (!v) { val.x = 0; val.y = 0; val.z = 0; val.w = 0; }
      *(int4v*)&A[tb + px * 34 + part8 * 4] = val;
    }
#pragma unroll
    for (int kk2 = 0; kk2 < 2; ++kk2) {
      int4v av = *(const int4v*)&A[tb + n16 * 34 + kk2 * 16 + q * 4];
      short8 af = __builtin_bit_cast(short8, av);
      int g = t * 8 + kk2 * 4 + q;
#pragma unroll
      for (int nt = 0; nt < 2; ++nt) {
        int4v bv = *(const int4v*)&Bgo[(g * 32 + nt * 16 + n16) * 4];
        short8 bfr = __builtin_bit_cast(short8, bv);
        acc2[nt] = __builtin_amdgcn_mfma_f32_16x16x32_bf16(af, bfr, acc2[nt], 0, 0, 0);
      }
    }
  }
  // offL aliases the wave's A region (A dead until phase-3 blends; in-order DS).
  float* offLw = (float*)&A[abase];
#pragma unroll
  for (int nt = 0; nt < 2; ++nt) {
    int o = nt * 16 + n16;
    if (o < NOFF) {
      float bv = off_b[o];
#pragma unroll
      for (int r = 0; r < 4; ++r) offLw[o * 16 + q * 4 + r] = acc2[nt][r] + bv;
    }
  }

  // ---------- phase 2: bilinear meta (wave-private) ----------
  int* Mw = M + cg * 144 * 4;
#pragma unroll
  for (int it = 0; it < 3; ++it) {
    int m = it * 64 + lane;
    if (m < 144) {
      int pxl = (unsigned)m / 9u;
      int t = m - pxl * 9;
      float dy = offLw[(2 * t) * 16 + pxl];
      float dx = offLw[(2 * t + 1) * 16 + pxl];
      float py = (float)(h + t / 3 - 1) + dy;
      float pxf = (float)(w0 + p0 + pxl + (t % 3) - 1) + dx;
      float fy0 = floorf(py), fx0 = floorf(pxf);
      float ay = py - fy0, ax = pxf - fx0;
      int iy0 = (int)fy0, ix0 = (int)fx0;
      int iy1 = iy0 + 1, ix1 = ix0 + 1;
      float wy0 = 1.0f - ay, wy1 = ay, wx0 = 1.0f - ax, wx1 = ax;
      if (!(iy0 >= 0 && iy0 < HH)) wy0 = 0.0f;
      if (!(iy1 >= 0 && iy1 < HH)) wy1 = 0.0f;
      if (!(ix0 >= 0 && ix0 < WW)) wx0 = 0.0f;
      if (!(ix1 >= 0 && ix1 < WW)) wx1 = 0.0f;
      int cy0 = min(max(iy0, 0), HH - 1), cy1 = min(max(iy1, 0), HH - 1);
      int cx0 = min(max(ix0, 0), WW - 1), cx1 = min(max(ix1, 0), WW - 1);
      int4v mv;
      mv.x = (cy0 * WW + cx0) | ((cy0 * WW + cx1) << 16);
      mv.y = (cy1 * WW + cx0) | ((cy1 * WW + cx1) << 16);
      mv.z = (int)(bf16rne(wy0 * wx0) | (bf16rne(wy0 * wx1) << 16));
      mv.w = (int)(bf16rne(wy1 * wx0) | (bf16rne(wy1 * wx1) << 16));
      *(int4v*)&Mw[m * 4] = mv;
    }
  }

  // ---------- phase 3: per-tap gather (1-tap prefetch) + MFMA ----------
  int p8 = lane >> 3;
  int cq4 = (lane & 7) * 4;
  f32x4 acc[4] = {f32x4{0,0,0,0}, f32x4{0,0,0,0}, f32x4{0,0,0,0}, f32x4{0,0,0,0}};
  G_ISSUE(0, 0, 0)   G_ISSUE(1, 0, 1)
  G_ISSUE(2, 1, 0)   G_ISSUE(3, 1, 1)   G_BLEND(0, 0, 0)   G_BLEND(1, 0, 1)   MFMA_TAP(0)
  G_ISSUE(4, 2, 0)   G_ISSUE(5, 2, 1)   G_BLEND(2, 1, 0)   G_BLEND(3, 1, 1)   MFMA_TAP(1)
  G_ISSUE(6, 3, 0)   G_ISSUE(7, 3, 1)   G_BLEND(4, 2, 0)   G_BLEND(5, 2, 1)   MFMA_TAP(2)
  G_ISSUE(8, 4, 0)   G_ISSUE(9, 4, 1)   G_BLEND(6, 3, 0)   G_BLEND(7, 3, 1)   MFMA_TAP(3)
  G_ISSUE(10, 5, 0)  G_ISSUE(11, 5, 1)  G_BLEND(8, 4, 0)   G_BLEND(9, 4, 1)   MFMA_TAP(4)
  G_ISSUE(12, 6, 0)  G_ISSUE(13, 6, 1)  G_BLEND(10, 5, 0)  G_BLEND(11, 5, 1)  MFMA_TAP(5)
  G_ISSUE(14, 7, 0)  G_ISSUE(15, 7, 1)  G_BLEND(12, 6, 0)  G_BLEND(13, 6, 1)  MFMA_TAP(6)
  G_ISSUE(16, 8, 0)  G_ISSUE(17, 8, 1)  G_BLEND(14, 7, 0)  G_BLEND(15, 7, 1)  MFMA_TAP(7)
  G_BLEND(16, 8, 0)  G_BLEND(17, 8, 1)  MFMA_TAP(8)

  // ---------- epilogue: bf16 y store + per-block stats partials ----------
  float* SW = (float*)&A[abase];   // aliases A buf0 (reads done; in-order DS)
#pragma unroll
  for (int nt = 0; nt < 4; ++nt) {
    int o = nt * 16 + n16;
    float bv = dc_b[o];
    f32x4 r;
    float s = 0.0f, ss = 0.0f;
#pragma unroll
    for (int r0 = 0; r0 < 4; ++r0) {
      r[r0] = acc[nt][r0] + bv;
      s += r[r0];
      ss += r[r0] * r[r0];
    }
    unsigned pk0 = __builtin_amdgcn_perm(__float_as_uint(r[1]) + 0x8000u,
                                         __float_as_uint(r[0]) + 0x8000u,
                                         0x07060302u);
    unsigned pk1 = __builtin_amdgcn_perm(__float_as_uint(r[3]) + 0x8000u,
                                         __float_as_uint(r[2]) + 0x8000u,
                                         0x07060302u);
    uint2v pk; pk.x = pk0; pk.y = pk1;
    *(uint2v*)&ybuf[(size_t)(b * OO + o) * (HWSZ / 2) + ((hw0 + p0) >> 1) + q * 2] = pk;
    s += __shfl_xor(s, 16);  s += __shfl_xor(s, 32);
    ss += __shfl_xor(ss, 16); ss += __shfl_xor(ss, 32);
    if (lane < 16) {   // lane == n16
      SW[nt * 16 + lane] = s;
      SW[64 + nt * 16 + lane] = ss;
    }
  }
  __syncthreads();
  // Slot-major partials: part[slot*1024 + bid] so norm's fold is contiguous.
  if (threadIdx.x < 64) {
    float ts = 0.0f, tq = 0.0f;
#pragma unroll
    for (int wv = 0; wv < 4; ++wv) {
      const float* Sv = (const float*)&A[wv * 1088];
      ts += Sv[threadIdx.x];
      tq += Sv[64 + threadIdx.x];
    }
    part[(size_t)threadIdx.x * 1024 + blockIdx.x] = ts;
    part[(size_t)(64 + threadIdx.x) * 1024 + blockIdx.x] = tq;
  }
}

// Norm + in-kernel stats fold. 8 outputs/thread (grid 2048): halves the
// number of redundant per-block part-folds and doubles streaming ILP.
__global__ __launch_bounds__(256) void norm_kernel(
    const unsigned int* __restrict__ ybuf, const float* __restrict__ part,
    const float* __restrict__ gamma, const float* __restrict__ beta,
    float* __restrict__ out) {
  __shared__ float red[16];
  int gid = blockIdx.x * 256 + threadIdx.x;   // int4v-granule id (8 bf16 vals)
  int o = (blockIdx.x >> 3) & 63;             // block-uniform channel
  float4 v4 = ((const float4*)(part + (size_t)o * 1024))[threadIdx.x];
  float4 w4 = ((const float4*)(part + (size_t)(64 + o) * 1024))[threadIdx.x];
  float s = v4.x + v4.y + v4.z + v4.w;
  float sq = w4.x + w4.y + w4.z + w4.w;
#pragma unroll
  for (int off = 1; off < 64; off <<= 1) {
    s += __shfl_xor(s, off);
    sq += __shfl_xor(sq, off);
  }
  if ((threadIdx.x & 63) == 0) {
    int w = threadIdx.x >> 6;
    red[w] = s;
    red[8 + w] = sq;
  }
  __syncthreads();
  float sm = red[0] + red[1] + red[2] + red[3];
  float sqq = red[8] + red[9] + red[10] + red[11];

  const float invN = 1.0f / (float)(BB * HWSZ);
  float mean = sm * invN;
  float var = sqq * invN - mean * mean;
  float rstd = rsqrtf(var + 1e-5f);
  float g = gamma[o] * rstd;
  float bta = beta[o] - mean * g;
  int4v v = ((const int4v*)ybuf)[gid];
  float4 r0, r1;
  r0.x = fmaxf(bf16lo((unsigned)v.x) * g + bta, 0.0f);
  r0.y = fmaxf(bf16hi((unsigned)v.x) * g + bta, 0.0f);
  r0.z = fmaxf(bf16lo((unsigned)v.y) * g + bta, 0.0f);
  r0.w = fmaxf(bf16hi((unsigned)v.y) * g + bta, 0.0f);
  r1.x = fmaxf(bf16lo((unsigned)v.z) * g + bta, 0.0f);
  r1.y = fmaxf(bf16hi((unsigned)v.z) * g + bta, 0.0f);
  r1.z = fmaxf(bf16lo((unsigned)v.w) * g + bta, 0.0f);
  r1.w = fmaxf(bf16hi((unsigned)v.w) * g + bta, 0.0f);
  ((float4*)out)[gid * 2] = r0;
  ((float4*)out)[gid * 2 + 1] = r1;
}

extern "C" void kernel_launch(void* const* d_in, const int* in_sizes, int n_in,
                              void* d_out, int out_size, void* d_ws, size_t ws_size,
                              hipStream_t stream) {
  const float* x     = (const float*)d_in[0];
  const float* off_w = (const float*)d_in[1];
  const float* off_b = (const float*)d_in[2];
  const float* dc_w  = (const float*)d_in[3];
  const float* dc_b  = (const float*)d_in[4];
  const float* gamma = (const float*)d_in[5];
  const float* beta  = (const float*)d_in[6];
  float* ws = (float*)d_ws;
  int*   Bg     = (int*)(ws + WS_BG);
  int*   Bgo    = (int*)(ws + WS_BGO);
  unsigned int* ybuf = (unsigned int*)(ws + WS_YBUF);
  float* part   = ws + WS_PART;
  float* out = (float*)d_out;
  // d_out (16 MB fp32) doubles as NHWC-bf16 xTu scratch (8 MB); dead before
  // norm writes out.
  unsigned int* xTu = (unsigned int*)d_out;

  prep_kernel<<<BB * HH * 2 + 64, 256, 0, stream>>>(x, off_w, dc_w, xTu, Bg, Bgo);
  fused_kernel<<<BB * HWSZ / 64, 256, 0, stream>>>(xTu, Bg, Bgo, off_b, dc_b, ybuf, part);
  norm_kernel<<<BB * OO * HWSZ / (8 * 256), 256, 0, stream>>>(ybuf, part, gamma, beta, out);
}

// Round 10
// 119.134 us; speedup vs baseline: 19.2195x; 1.0188x over previous
//
#include <hip/hip_runtime.h>

#define HH 128
#define WW 128
#define HWSZ (HH * WW)
#define CC 64
#define OO 64
#define BB 4
#define NOFF 18
#define KK 576          // C*9

// ws layout (dword offsets)
#define WS_BG     0                         // 72*64*4 = 18432 (deform weights, quad-packed)
#define WS_BGO    18432                     // 72*32*4 = 9216  (offset weights, quad-packed, N=32)
#define WS_YBUF   27776                     // bf16 y: 4*64*16384*2B = 8 MB (2097152 dwords)
#define WS_PART   2125952                   // 128 slots x 1024 blocks (slot-major) = 512 KB

typedef __attribute__((ext_vector_type(8))) short short8;
typedef __attribute__((ext_vector_type(4))) int int4v;
typedef __attribute__((ext_vector_type(2))) unsigned int uint2v;
typedef __attribute__((ext_vector_type(4))) float f32x4;

__device__ inline unsigned bf16rne(float f) {
  unsigned u = __float_as_uint(f);
  u += 0x7fff + ((u >> 16) & 1);
  return u >> 16;
}

__device__ inline float bf16lo(unsigned u) { return __uint_as_float(u << 16); }
__device__ inline float bf16hi(unsigned u) { return __uint_as_float(u & 0xffff0000u); }

// NHWC-bf16 transpose (blocks 0..1023, 64c x 64w tiles) + weight repack
// (blocks 1024..1087).
__global__ __launch_bounds__(256) void prep_kernel(
    const float* __restrict__ x, const float* __restrict__ off_w,
    const float* __restrict__ dc_w, unsigned int* __restrict__ xTu,
    int* __restrict__ Bg, int* __restrict__ Bgo) {
  int bid = blockIdx.x;
  if (bid < BB * HH * 2) {
    __shared__ float T[CC][64 + 1];
    int b = bid >> 8, rem = bid & 255;
    int h = rem >> 1, wh = (rem & 1) * 64;
    const float* xp = x + (size_t)b * CC * HWSZ + h * WW + wh;
    int j = threadIdx.x;
    // 64c x 64w tile = 1024 float4 slots; 4 per thread, fully coalesced.
#pragma unroll
    for (int i = 0; i < 4; ++i) {
      int l = i * 256 + j;
      int c = l >> 4, w4 = l & 15;
      float4 v = *(const float4*)(xp + (size_t)c * HWSZ + w4 * 4);
      T[c][w4 * 4 + 0] = v.x;
      T[c][w4 * 4 + 1] = v.y;
      T[c][w4 * 4 + 2] = v.z;
      T[c][w4 * 4 + 3] = v.w;
    }
    __syncthreads();
    int c2 = threadIdx.x & 31, wq = threadIdx.x >> 5;
    unsigned int* op = xTu + ((size_t)(b * HH + h) * WW + wh) * 32;
#pragma unroll 8
    for (int i = 0; i < 8; ++i) {
      int w = i * 8 + wq;
      unsigned pk = bf16rne(T[2 * c2][w]) | (bf16rne(T[2 * c2 + 1][w]) << 16);
      op[w * 32 + c2] = pk;
    }
  } else {
    int pb = bid - BB * HH * 2;
    int tid = pb * 256 + threadIdx.x;
    int stride = 64 * 256;
    for (int i = tid; i < 72 * 64 * 4; i += stride) {
      int j = i & 3, o = (i >> 2) & 63, g = i >> 8;
      int k2 = g * 4 + j, t = k2 >> 5, jj = k2 & 31;
      unsigned lo = bf16rne(dc_w[o * KK + (2 * jj) * 9 + t]);
      unsigned hi = bf16rne(dc_w[o * KK + (2 * jj + 1) * 9 + t]);
      Bg[i] = (int)(lo | (hi << 16));
    }
    for (int i = tid; i < 72 * 32 * 4; i += stride) {
      int j = i & 3, o = (i >> 2) & 31, g = i >> 7;
      int k2 = g * 4 + j, t = k2 >> 5, jj = k2 & 31;
      unsigned pk = 0;
      if (o < NOFF) {
        unsigned lo = bf16rne(off_w[o * KK + (2 * jj) * 9 + t]);
        unsigned hi = bf16rne(off_w[o * KK + (2 * jj + 1) * 9 + t]);
        pk = lo | (hi << 16);
      }
      Bgo[i] = (int)pk;
    }
  }
}

// ---- phase-3 gather macros --------------------------------------------------
// Lane map: p8 = lane>>3 (pixel slot), cq4 = (lane&7)*4 (channel-quad dword).
// Per-tap double-buffered A: wave region A[cg*1088], buf (t&1)*544,
// row stride 34 dwords (34 = 2 mod 32 -> ~2-4 way banks).
#define G_ISSUE(i, T, PH)                                                     \
  int4v m##i, da##i, db##i, dcv##i, dd##i;                                    \
  {                                                                           \
    m##i = *(const int4v*)&Mw[(((PH) * 8 + p8) * 9 + (T)) * 4];               \
    unsigned x_ = (unsigned)m##i.x, y_ = (unsigned)m##i.y;                    \
    da##i  = *(const int4v*)&xbu[(x_ & 0xffffu) * 32 + cq4];                  \
    db##i  = *(const int4v*)&xbu[(x_ >> 16) * 32 + cq4];                      \
    dcv##i = *(const int4v*)&xbu[(y_ & 0xffffu) * 32 + cq4];                  \
    dd##i  = *(const int4v*)&xbu[(y_ >> 16) * 32 + cq4];                      \
  }

#define G_BLEND(i, T, PH)                                                     \
  {                                                                           \
    float w00_ = __uint_as_float(((unsigned)m##i.z) << 16);                   \
    float w01_ = __uint_as_float(((unsigned)m##i.z) & 0xffff0000u);           \
    float w10_ = __uint_as_float(((unsigned)m##i.w) << 16);                   \
    float w11_ = __uint_as_float(((unsigned)m##i.w) & 0xffff0000u);           \
    int4v pk_;                                                                \
    _Pragma("unroll")                                                         \
    for (int j = 0; j < 4; ++j) {                                             \
      float slo_ = w00_ * __uint_as_float(((unsigned)da##i[j]) << 16);        \
      slo_ = fmaf(w01_, __uint_as_float(((unsigned)db##i[j]) << 16), slo_);   \
      slo_ = fmaf(w10_, __uint_as_float(((unsigned)dcv##i[j]) << 16), slo_);  \
      slo_ = fmaf(w11_, __uint_as_float(((unsigned)dd##i[j]) << 16), slo_);   \
      float shi_ = w00_ * __uint_as_float(((unsigned)da##i[j]) & 0xffff0000u);\
      shi_ = fmaf(w01_, __uint_as_float(((unsigned)db##i[j]) & 0xffff0000u), shi_);\
      shi_ = fmaf(w10_, __uint_as_float(((unsigned)dcv##i[j]) & 0xffff0000u), shi_);\
      shi_ = fmaf(w11_, __uint_as_float(((unsigned)dd##i[j]) & 0xffff0000u), shi_);\
      pk_[j] = (int)__builtin_amdgcn_perm(__float_as_uint(shi_) + 0x8000u,    \
                                          __float_as_uint(slo_) + 0x8000u,    \
                                          0x07060302u);                       \
    }                                                                         \
    *(int4v*)&A[abase + ((T) & 1) * 544 + ((PH) * 8 + p8) * 34 + cq4] = pk_;  \
  }

#define MFMA_TAP(T)                                                           \
  {                                                                           \
    _Pragma("unroll")                                                         \
    for (int kk2 = 0; kk2 < 2; ++kk2) {                                       \
      int4v av = *(const int4v*)&A[abase + ((T) & 1) * 544 + n16 * 34 + kk2 * 16 + q * 4]; \
      short8 af = __builtin_bit_cast(short8, av);                             \
      int g = (T) * 8 + kk2 * 4 + q;                                          \
      _Pragma("unroll")                                                       \
      for (int nt = 0; nt < 4; ++nt) {                                        \
        int4v bv = *(const int4v*)&Bg[(g * 64 + nt * 16 + n16) * 4];          \
        short8 bfr = __builtin_bit_cast(short8, bv);                          \
        acc[nt] = __builtin_amdgcn_mfma_f32_16x16x32_bf16(af, bfr, acc[nt], 0, 0, 0); \
      }                                                                       \
    }                                                                         \
  }

// Fused offset-conv + deform-conv + BN-partials (R9 form + T1 XCD swizzle).
// T1: default dispatch round-robins blocks across 8 XCDs with private L2s;
// neighbor blocks (h, h+-1) share 2 of 3 gather rows, so the default mapping
// re-fetches those rows from L3 on every XCD (~3-6x duplication -> L3-BW
// bound). Swizzle gives XCD k a contiguous 128-block chunk = 64 consecutive
// h-rows of one image = 1 MB row window, L2-resident. 1024 % 8 == 0 ->
// simple bijective form is safe. part[] stays indexed by hardware blockIdx
// (fold is order-independent; arithmetic identical).
__global__ __launch_bounds__(256, 6) void fused_kernel(
    const unsigned int* __restrict__ xTu, const int* __restrict__ Bg,
    const int* __restrict__ Bgo, const float* __restrict__ off_b,
    const float* __restrict__ dc_b, unsigned int* __restrict__ ybuf,
    float* __restrict__ part) {
  __shared__ __align__(16) int A[4 * 1088];   // 17.4 KB: 4 waves x 2 bufs x 16px x 34dw
  __shared__ __align__(16) int M[4 * 144 * 4]; // 9.2 KB meta

  int cg = threadIdx.x >> 6, lane = threadIdx.x & 63;
  int wg = (int)blockIdx.x;
  int swz = (wg & 7) * 128 + (wg >> 3);   // XCD-contiguous logical block id
  int b = swz >> 8, rem = swz & 255;
  int h = rem >> 1, w0 = (rem & 1) * 64;
  int hw0 = h * WW + w0;
  int p0 = cg * 16;
  int abase = cg * 1088;
  int n16 = lane & 15, q = lane >> 4;
  int pg = lane >> 3, part8 = lane & 7;
  const unsigned int* xbu = xTu + (size_t)b * HWSZ * 32;

  // ---------- phase 1: offset conv (per-tap im2col + MFMA) ----------
  f32x4 acc2[2] = {f32x4{0, 0, 0, 0}, f32x4{0, 0, 0, 0}};
#pragma unroll
  for (int t = 0; t < 9; ++t) {
    int ky = t / 3 - 1, kx = t % 3 - 1;
    int cy = h + ky;
    bool vy = (cy >= 0) && (cy < HH);
    int cys = min(max(cy, 0), HH - 1);
    int tb = abase + (t & 1) * 544;
#pragma unroll
    for (int i = 0; i < 2; ++i) {
      int px = i * 8 + pg;
      int cx = w0 + p0 + px + kx;
      bool v = vy && (cx >= 0) && (cx < WW);
      int cxs = min(max(cx, 0), WW - 1);
      int4v val = *(const int4v*)&xbu[(cys * WW + cxs) * 32 + part8 * 4];
      if (!v) { val.x = 0; val.y = 0; val.z = 0; val.w = 0; }
      *(int4v*)&A[tb + px * 34 + part8 * 4] = val;
    }
#pragma unroll
    for (int kk2 = 0; kk2 < 2; ++kk2) {
      int4v av = *(const int4v*)&A[tb + n16 * 34 + kk2 * 16 + q * 4];
      short8 af = __builtin_bit_cast(short8, av);
      int g = t * 8 + kk2 * 4 + q;
#pragma unroll
      for (int nt = 0; nt < 2; ++nt) {
        int4v bv = *(const int4v*)&Bgo[(g * 32 + nt * 16 + n16) * 4];
        short8 bfr = __builtin_bit_cast(short8, bv);
        acc2[nt] = __builtin_amdgcn_mfma_f32_16x16x32_bf16(af, bfr, acc2[nt], 0, 0, 0);
      }
    }
  }
  // offL aliases the wave's A region (A dead until phase-3 blends; in-order DS).
  float* offLw = (float*)&A[abase];
#pragma unroll
  for (int nt = 0; nt < 2; ++nt) {
    int o = nt * 16 + n16;
    if (o < NOFF) {
      float bv = off_b[o];
#pragma unroll
      for (int r = 0; r < 4; ++r) offLw[o * 16 + q * 4 + r] = acc2[nt][r] + bv;
    }
  }

  // ---------- phase 2: bilinear meta (wave-private) ----------
  int* Mw = M + cg * 144 * 4;
#pragma unroll
  for (int it = 0; it < 3; ++it) {
    int m = it * 64 + lane;
    if (m < 144) {
      int pxl = (unsigned)m / 9u;
      int t = m - pxl * 9;
      float dy = offLw[(2 * t) * 16 + pxl];
      float dx = offLw[(2 * t + 1) * 16 + pxl];
      float py = (float)(h + t / 3 - 1) + dy;
      float pxf = (float)(w0 + p0 + pxl + (t % 3) - 1) + dx;
      float fy0 = floorf(py), fx0 = floorf(pxf);
      float ay = py - fy0, ax = pxf - fx0;
      int iy0 = (int)fy0, ix0 = (int)fx0;
      int iy1 = iy0 + 1, ix1 = ix0 + 1;
      float wy0 = 1.0f - ay, wy1 = ay, wx0 = 1.0f - ax, wx1 = ax;
      if (!(iy0 >= 0 && iy0 < HH)) wy0 = 0.0f;
      if (!(iy1 >= 0 && iy1 < HH)) wy1 = 0.0f;
      if (!(ix0 >= 0 && ix0 < WW)) wx0 = 0.0f;
      if (!(ix1 >= 0 && ix1 < WW)) wx1 = 0.0f;
      int cy0 = min(max(iy0, 0), HH - 1), cy1 = min(max(iy1, 0), HH - 1);
      int cx0 = min(max(ix0, 0), WW - 1), cx1 = min(max(ix1, 0), WW - 1);
      int4v mv;
      mv.x = (cy0 * WW + cx0) | ((cy0 * WW + cx1) << 16);
      mv.y = (cy1 * WW + cx0) | ((cy1 * WW + cx1) << 16);
      mv.z = (int)(bf16rne(wy0 * wx0) | (bf16rne(wy0 * wx1) << 16));
      mv.w = (int)(bf16rne(wy1 * wx0) | (bf16rne(wy1 * wx1) << 16));
      *(int4v*)&Mw[m * 4] = mv;
    }
  }

  // ---------- phase 3: per-tap gather (1-tap prefetch) + MFMA ----------
  int p8 = lane >> 3;
  int cq4 = (lane & 7) * 4;
  f32x4 acc[4] = {f32x4{0,0,0,0}, f32x4{0,0,0,0}, f32x4{0,0,0,0}, f32x4{0,0,0,0}};
  G_ISSUE(0, 0, 0)   G_ISSUE(1, 0, 1)
  G_ISSUE(2, 1, 0)   G_ISSUE(3, 1, 1)   G_BLEND(0, 0, 0)   G_BLEND(1, 0, 1)   MFMA_TAP(0)
  G_ISSUE(4, 2, 0)   G_ISSUE(5, 2, 1)   G_BLEND(2, 1, 0)   G_BLEND(3, 1, 1)   MFMA_TAP(1)
  G_ISSUE(6, 3, 0)   G_ISSUE(7, 3, 1)   G_BLEND(4, 2, 0)   G_BLEND(5, 2, 1)   MFMA_TAP(2)
  G_ISSUE(8, 4, 0)   G_ISSUE(9, 4, 1)   G_BLEND(6, 3, 0)   G_BLEND(7, 3, 1)   MFMA_TAP(3)
  G_ISSUE(10, 5, 0)  G_ISSUE(11, 5, 1)  G_BLEND(8, 4, 0)   G_BLEND(9, 4, 1)   MFMA_TAP(4)
  G_ISSUE(12, 6, 0)  G_ISSUE(13, 6, 1)  G_BLEND(10, 5, 0)  G_BLEND(11, 5, 1)  MFMA_TAP(5)
  G_ISSUE(14, 7, 0)  G_ISSUE(15, 7, 1)  G_BLEND(12, 6, 0)  G_BLEND(13, 6, 1)  MFMA_TAP(6)
  G_ISSUE(16, 8, 0)  G_ISSUE(17, 8, 1)  G_BLEND(14, 7, 0)  G_BLEND(15, 7, 1)  MFMA_TAP(7)
  G_BLEND(16, 8, 0)  G_BLEND(17, 8, 1)  MFMA_TAP(8)

  // ---------- epilogue: bf16 y store + per-block stats partials ----------
  float* SW = (float*)&A[abase];   // aliases A buf0 (reads done; in-order DS)
#pragma unroll
  for (int nt = 0; nt < 4; ++nt) {
    int o = nt * 16 + n16;
    float bv = dc_b[o];
    f32x4 r;
    float s = 0.0f, ss = 0.0f;
#pragma unroll
    for (int r0 = 0; r0 < 4; ++r0) {
      r[r0] = acc[nt][r0] + bv;
      s += r[r0];
      ss += r[r0] * r[r0];
    }
    unsigned pk0 = __builtin_amdgcn_perm(__float_as_uint(r[1]) + 0x8000u,
                                         __float_as_uint(r[0]) + 0x8000u,
                                         0x07060302u);
    unsigned pk1 = __builtin_amdgcn_perm(__float_as_uint(r[3]) + 0x8000u,
                                         __float_as_uint(r[2]) + 0x8000u,
                                         0x07060302u);
    uint2v pk; pk.x = pk0; pk.y = pk1;
    *(uint2v*)&ybuf[(size_t)(b * OO + o) * (HWSZ / 2) + ((hw0 + p0) >> 1) + q * 2] = pk;
    s += __shfl_xor(s, 16);  s += __shfl_xor(s, 32);
    ss += __shfl_xor(ss, 16); ss += __shfl_xor(ss, 32);
    if (lane < 16) {   // lane == n16
      SW[nt * 16 + lane] = s;
      SW[64 + nt * 16 + lane] = ss;
    }
  }
  __syncthreads();
  // Slot-major partials: part[slot*1024 + hw_bid] so norm's fold is contiguous.
  if (threadIdx.x < 64) {
    float ts = 0.0f, tq = 0.0f;
#pragma unroll
    for (int wv = 0; wv < 4; ++wv) {
      const float* Sv = (const float*)&A[wv * 1088];
      ts += Sv[threadIdx.x];
      tq += Sv[64 + threadIdx.x];
    }
    part[(size_t)threadIdx.x * 1024 + blockIdx.x] = ts;
    part[(size_t)(64 + threadIdx.x) * 1024 + blockIdx.x] = tq;
  }
}

// Norm + in-kernel stats fold. 8 outputs/thread (grid 2048).
__global__ __launch_bounds__(256) void norm_kernel(
    const unsigned int* __restrict__ ybuf, const float* __restrict__ part,
    const float* __restrict__ gamma, const float* __restrict__ beta,
    float* __restrict__ out) {
  __shared__ float red[16];
  int gid = blockIdx.x * 256 + threadIdx.x;   // int4v-granule id (8 bf16 vals)
  int o = (blockIdx.x >> 3) & 63;             // block-uniform channel
  float4 v4 = ((const float4*)(part + (size_t)o * 1024))[threadIdx.x];
  float4 w4 = ((const float4*)(part + (size_t)(64 + o) * 1024))[threadIdx.x];
  float s = v4.x + v4.y + v4.z + v4.w;
  float sq = w4.x + w4.y + w4.z + w4.w;
#pragma unroll
  for (int off = 1; off < 64; off <<= 1) {
    s += __shfl_xor(s, off);
    sq += __shfl_xor(sq, off);
  }
  if ((threadIdx.x & 63) == 0) {
    int w = threadIdx.x >> 6;
    red[w] = s;
    red[8 + w] = sq;
  }
  __syncthreads();
  float sm = red[0] + red[1] + red[2] + red[3];
  float sqq = red[8] + red[9] + red[10] + red[11];

  const float invN = 1.0f / (float)(BB * HWSZ);
  float mean = sm * invN;
  float var = sqq * invN - mean * mean;
  float rstd = rsqrtf(var + 1e-5f);
  float g = gamma[o] * rstd;
  float bta = beta[o] - mean * g;
  int4v v = ((const int4v*)ybuf)[gid];
  float4 r0, r1;
  r0.x = fmaxf(bf16lo((unsigned)v.x) * g + bta, 0.0f);
  r0.y = fmaxf(bf16hi((unsigned)v.x) * g + bta, 0.0f);
  r0.z = fmaxf(bf16lo((unsigned)v.y) * g + bta, 0.0f);
  r0.w = fmaxf(bf16hi((unsigned)v.y) * g + bta, 0.0f);
  r1.x = fmaxf(bf16lo((unsigned)v.z) * g + bta, 0.0f);
  r1.y = fmaxf(bf16hi((unsigned)v.z) * g + bta, 0.0f);
  r1.z = fmaxf(bf16lo((unsigned)v.w) * g + bta, 0.0f);
  r1.w = fmaxf(bf16hi((unsigned)v.w) * g + bta, 0.0f);
  ((float4*)out)[gid * 2] = r0;
  ((float4*)out)[gid * 2 + 1] = r1;
}

extern "C" void kernel_launch(void* const* d_in, const int* in_sizes, int n_in,
                              void* d_out, int out_size, void* d_ws, size_t ws_size,
                              hipStream_t stream) {
  const float* x     = (const float*)d_in[0];
  const float* off_w = (const float*)d_in[1];
  const float* off_b = (const float*)d_in[2];
  const float* dc_w  = (const float*)d_in[3];
  const float* dc_b  = (const float*)d_in[4];
  const float* gamma = (const float*)d_in[5];
  const float* beta  = (const float*)d_in[6];
  float* ws = (float*)d_ws;
  int*   Bg     = (int*)(ws + WS_BG);
  int*   Bgo    = (int*)(ws + WS_BGO);
  unsigned int* ybuf = (unsigned int*)(ws + WS_YBUF);
  float* part   = ws + WS_PART;
  float* out = (float*)d_out;
  // d_out (16 MB fp32) doubles as NHWC-bf16 xTu scratch (8 MB); dead before
  // norm writes out.
  unsigned int* xTu = (unsigned int*)d_out;

  prep_kernel<<<BB * HH * 2 + 64, 256, 0, stream>>>(x, off_w, dc_w, xTu, Bg, Bgo);
  fused_kernel<<<BB * HWSZ / 64, 256, 0, stream>>>(xTu, Bg, Bgo, off_b, dc_b, ybuf, part);
  norm_kernel<<<BB * OO * HWSZ / (8 * 256), 256, 0, stream>>>(ybuf, part, gamma, beta, out);
}